// Round 7
// baseline (528.834 us; speedup 1.0000x reference)
//
#include <hip/hip_runtime.h>

#define N_NODES 100000
#define N_EDGES 1600000
#define F_IN    128
#define HID     64
#define N_CLASS 40
#define NEG_SLOPE 0.2f
#define ET (N_EDGES + N_NODES)          // 1,700,000
#define ROW_BLOCKS ((N_NODES + 63) / 64)

// ---- 2-level radix partition geometry ----
#define NCB   7                          // coarse buckets (dst >> 14)
#define CAP1  294912                     // per-coarse capacity (= 144*2048)
#define BPC   144                        // part2 blocks per coarse bucket
#define NFB   782                        // fine buckets (dst >> 7), 128-node ranges
#define CAPF  2624                       // per-fine capacity (mu 2176 + ~10 sigma)
#define NT1   ((ET + 2047) / 2048)       // 831 part1 tiles

__device__ __forceinline__ unsigned int f2bf(float f) {  // fp32 -> bf16 (RNE)
    unsigned int u = __float_as_uint(f);
    return (u + 0x7fffu + ((u >> 16) & 1u)) >> 16;
}

// ---------------------------------------------------------------------------
// h0 = relu(x @ W1 + b1). 4 waves share a 64-row LDS tile; wave w computes
// output cols [16w,16w+16). W via wave-uniform scalar loads (SGPR operands).
// ---------------------------------------------------------------------------
__global__ __launch_bounds__(256) void k_lin1(const float* __restrict__ x,
        const float* __restrict__ W1, const float* __restrict__ b1,
        float* __restrict__ out) {
    __shared__ float xs[64 * 68];
    int t = threadIdx.x;
    int lane = t & 63;
    int w = t >> 6;
    int cbase = w * 16;
    int base = blockIdx.x * 64;
    int rem = N_NODES - base; if (rem > 64) rem = 64;

    float acc[16];
    #pragma unroll
    for (int c = 0; c < 16; ++c) acc[c] = b1[cbase + c];

    for (int half = 0; half < 2; ++half) {
        __syncthreads();
        #pragma unroll
        for (int j = 0; j < 4; ++j) {
            int idx = j * 256 + t;            // 1024 float4s in the tile
            int r = idx >> 4, c4 = idx & 15;
            int gr = base + r; if (gr >= N_NODES) gr = N_NODES - 1;
            float4 v = *(const float4*)(x + (size_t)gr * F_IN + half * 64 + c4 * 4);
            *(float4*)(xs + r * 68 + c4 * 4) = v;
        }
        __syncthreads();
        const float* xrow = xs + lane * 68;
        #pragma unroll 4
        for (int k4 = 0; k4 < 16; ++k4) {
            float4 xv = *(const float4*)(xrow + 4 * k4);
            int kb = (half * 64 + 4 * k4) * HID + cbase;
            #pragma unroll
            for (int c = 0; c < 16; ++c) {
                acc[c] = fmaf(xv.x, W1[kb + c],           acc[c]);
                acc[c] = fmaf(xv.y, W1[kb + HID + c],     acc[c]);
                acc[c] = fmaf(xv.z, W1[kb + 2 * HID + c], acc[c]);
                acc[c] = fmaf(xv.w, W1[kb + 3 * HID + c], acc[c]);
            }
        }
    }
    __syncthreads();
    #pragma unroll
    for (int c4 = 0; c4 < 4; ++c4) {
        float4 o;
        o.x = fmaxf(acc[4 * c4 + 0], 0.f);
        o.y = fmaxf(acc[4 * c4 + 1], 0.f);
        o.z = fmaxf(acc[4 * c4 + 2], 0.f);
        o.w = fmaxf(acc[4 * c4 + 3], 0.f);
        *(float4*)(xs + lane * 68 + cbase + c4 * 4) = o;
    }
    __syncthreads();
    #pragma unroll
    for (int j = 0; j < 4; ++j) {
        int idx = j * 256 + t;
        if (idx < rem * 16) {
            int r = idx >> 4, c4 = idx & 15;
            float4 v = *(const float4*)(xs + r * 68 + c4 * 4);
            *(float4*)(out + (size_t)(base + r) * HID + c4 * 4) = v;
        }
    }
}

// ---------------------------------------------------------------------------
// h = hin @ Wc -> bf16 hb ; as_ = h@att_src ; ad_ = h@att_dst.
// 4-wave column split; att dots via per-wave partials + LDS reduce.
// ---------------------------------------------------------------------------
__global__ __launch_bounds__(256) void k_gemm_att(const float* __restrict__ hin,
        const float* __restrict__ Wc,
        const float* __restrict__ att_s, const float* __restrict__ att_d,
        unsigned short* __restrict__ hb, float* __restrict__ as_,
        float* __restrict__ ad_) {
    __shared__ float xs[64 * 68];
    __shared__ float ps[2][4][64];
    int t = threadIdx.x;
    int lane = t & 63;
    int w = t >> 6;
    int cbase = w * 16;
    int base = blockIdx.x * 64;
    int rem = N_NODES - base; if (rem > 64) rem = 64;

    #pragma unroll
    for (int j = 0; j < 4; ++j) {
        int idx = j * 256 + t;
        int r = idx >> 4, c4 = idx & 15;
        int gr = base + r; if (gr >= N_NODES) gr = N_NODES - 1;
        float4 v = *(const float4*)(hin + (size_t)gr * HID + c4 * 4);
        *(float4*)(xs + r * 68 + c4 * 4) = v;
    }
    __syncthreads();

    float acc[16];
    #pragma unroll
    for (int c = 0; c < 16; ++c) acc[c] = 0.f;
    const float* xrow = xs + lane * 68;
    #pragma unroll 4
    for (int k4 = 0; k4 < 16; ++k4) {
        float4 xv = *(const float4*)(xrow + 4 * k4);
        int kb = 4 * k4 * HID + cbase;
        #pragma unroll
        for (int c = 0; c < 16; ++c) {
            acc[c] = fmaf(xv.x, Wc[kb + c],           acc[c]);
            acc[c] = fmaf(xv.y, Wc[kb + HID + c],     acc[c]);
            acc[c] = fmaf(xv.z, Wc[kb + 2 * HID + c], acc[c]);
            acc[c] = fmaf(xv.w, Wc[kb + 3 * HID + c], acc[c]);
        }
    }
    float s1 = 0.f, s2 = 0.f;
    #pragma unroll
    for (int c = 0; c < 16; ++c) {
        s1 = fmaf(acc[c], att_s[cbase + c], s1);
        s2 = fmaf(acc[c], att_d[cbase + c], s2);
    }
    ps[0][w][lane] = s1;
    ps[1][w][lane] = s2;
    __syncthreads();
    if (t < 64) {
        float a = ps[0][0][t] + ps[0][1][t] + ps[0][2][t] + ps[0][3][t];
        if (t < rem) as_[base + t] = a;
    } else if (t < 128) {
        int L = t - 64;
        float a = ps[1][0][L] + ps[1][1][L] + ps[1][2][L] + ps[1][3][L];
        if (L < rem) ad_[base + L] = a;
    }
    // acc -> xs (input tile dead past the ps barrier)
    #pragma unroll
    for (int c4 = 0; c4 < 4; ++c4) {
        float4 o;
        o.x = acc[4 * c4 + 0]; o.y = acc[4 * c4 + 1];
        o.z = acc[4 * c4 + 2]; o.w = acc[4 * c4 + 3];
        *(float4*)(xs + lane * 68 + cbase + c4 * 4) = o;
    }
    __syncthreads();
    // pack bf16: 64 rows x 64 cols = 512 uint4 stores
    #pragma unroll
    for (int j = 0; j < 2; ++j) {
        int idx = j * 256 + t;
        int r = idx >> 3, g = idx & 7;
        if (r < rem) {
            const float* p = xs + r * 68 + g * 8;
            uint4 u;
            u.x = f2bf(p[0]) | (f2bf(p[1]) << 16);
            u.y = f2bf(p[2]) | (f2bf(p[3]) << 16);
            u.z = f2bf(p[4]) | (f2bf(p[5]) << 16);
            u.w = f2bf(p[6]) | (f2bf(p[7]) << 16);
            *(uint4*)(hb + (size_t)(base + r) * HID + g * 8) = u;
        }
    }
}

// ---------------------------------------------------------------------------
// Partition level 1: edges -> 7 coarse buckets (dst>>14).
// ---------------------------------------------------------------------------
__global__ __launch_bounds__(256) void k_part1(const int* __restrict__ ei,
        int* __restrict__ tail1, int2* __restrict__ buf1) {
    __shared__ int2 eb[2048];
    __shared__ int hist[NCB], lbase[NCB], loff[NCB], goff[NCB];
    int t = threadIdx.x;
    int tileBase = blockIdx.x * 2048;
    int total = ET - tileBase; if (total > 2048) total = 2048;
    if (t < NCB) hist[t] = 0;
    __syncthreads();

    int sr[8], dr[8];
    #pragma unroll
    for (int r = 0; r < 8; ++r) {
        int i = tileBase + r * 256 + t;
        int s = -1, d = -1;
        if (i < ET) {
            if (i < N_EDGES) { s = ei[i]; d = ei[N_EDGES + i]; }
            else             { s = d = i - N_EDGES; }
            atomicAdd(&hist[d >> 14], 1);
        }
        sr[r] = s; dr[r] = d;
    }
    __syncthreads();
    if (t == 0) {
        int run = 0;
        for (int b = 0; b < NCB; ++b) { lbase[b] = run; loff[b] = 0; run += hist[b]; }
    }
    __syncthreads();
    if (t < NCB && hist[t] > 0) goff[t] = atomicAdd(&tail1[t], hist[t]);
    #pragma unroll
    for (int r = 0; r < 8; ++r) {
        if (dr[r] >= 0) {
            int b = dr[r] >> 14;
            int p = lbase[b] + atomicAdd(&loff[b], 1);
            eb[p] = make_int2(sr[r], dr[r]);
        }
    }
    __syncthreads();
    for (int j = t; j < total; j += 256) {
        int2 e = eb[j];
        int b = e.y >> 14;
        buf1[(size_t)b * CAP1 + goff[b] + (j - lbase[b])] = e;
    }
}

// ---------------------------------------------------------------------------
// Partition level 2: coarse bucket -> 128 fine buckets (128-dst ranges).
// ---------------------------------------------------------------------------
__global__ __launch_bounds__(256) void k_part2(const int2* __restrict__ buf1,
        const int* __restrict__ tail1, int* __restrict__ fcnt,
        int2* __restrict__ buf2) {
    __shared__ int2 eb[2048];
    __shared__ int hist[128], lbase[128], loff[128], goff[128], sc[128];
    int t = threadIdx.x;
    int cb   = blockIdx.x / BPC;
    int tile = blockIdx.x % BPC;
    int n1 = tail1[cb];
    int base = tile * 2048;
    if (base >= n1) return;
    int total = n1 - base; if (total > 2048) total = 2048;
    if (t < 128) hist[t] = 0;
    __syncthreads();

    int sr[8], dr[8];
    #pragma unroll
    for (int r = 0; r < 8; ++r) {
        int i = base + r * 256 + t;
        int s = -1, d = -1;
        if (i < n1) {
            int2 e = buf1[(size_t)cb * CAP1 + i];
            s = e.x; d = e.y;
            atomicAdd(&hist[(d >> 7) & 127], 1);
        }
        sr[r] = s; dr[r] = d;
    }
    __syncthreads();
    if (t < 128) sc[t] = hist[t];
    __syncthreads();
    for (int off = 1; off < 128; off <<= 1) {
        int u = (t < 128 && t >= off) ? sc[t - off] : 0;
        __syncthreads();
        if (t < 128) sc[t] += u;
        __syncthreads();
    }
    if (t < 128) { lbase[t] = sc[t] - hist[t]; loff[t] = 0; }
    __syncthreads();
    if (t < 128 && hist[t] > 0)
        goff[t] = atomicAdd(&fcnt[cb * 128 + t], hist[t]);
    #pragma unroll
    for (int r = 0; r < 8; ++r) {
        if (dr[r] >= 0) {
            int f = (dr[r] >> 7) & 127;
            int p = lbase[f] + atomicAdd(&loff[f], 1);
            eb[p] = make_int2(sr[r], dr[r]);
        }
    }
    __syncthreads();
    for (int j = t; j < total; j += 256) {
        int2 e = eb[j];
        int f = (e.y >> 7) & 127;
        buf2[(size_t)(e.y >> 7) * CAPF + goff[f] + (j - lbase[f])] = e;
    }
}

// ---------------------------------------------------------------------------
// Scan of fine-bucket counts -> global bases; rowptr[N] = ET.
// ---------------------------------------------------------------------------
__global__ __launch_bounds__(1024) void k_fscan(const int* __restrict__ fcnt,
        int* __restrict__ fbase, int* __restrict__ rowptr) {
    __shared__ int s[1024];
    int t = threadIdx.x;
    int v = (t < NFB) ? fcnt[t] : 0;
    s[t] = v;
    __syncthreads();
    for (int off = 1; off < 1024; off <<= 1) {
        int u = (t >= off) ? s[t - off] : 0;
        __syncthreads();
        s[t] += u;
        __syncthreads();
    }
    if (t < NFB) fbase[t] = s[t] - v;
    if (t == 0) rowptr[N_NODES] = ET;
}

// ---------------------------------------------------------------------------
// Partition level 3: fine bucket -> exact per-node CSR.
// ---------------------------------------------------------------------------
__global__ __launch_bounds__(256) void k_part3(const int2* __restrict__ buf2,
        const int* __restrict__ fcnt, const int* __restrict__ fbase,
        int* __restrict__ rowptr, int* __restrict__ col) {
    __shared__ int2 eb[CAPF];
    __shared__ int cs[CAPF];
    __shared__ int hist[128], lbase[128], loff[128], sc[128];
    int t = threadIdx.x;
    int fb = blockIdx.x;
    int nF = fcnt[fb];
    int gb = fbase[fb];
    int dbase = fb * 128;
    if (t < 128) hist[t] = 0;
    __syncthreads();
    for (int j = t; j < nF; j += 256) {
        int2 e = buf2[(size_t)fb * CAPF + j];
        eb[j] = e;
        atomicAdd(&hist[e.y - dbase], 1);
    }
    __syncthreads();
    if (t < 128) sc[t] = hist[t];
    __syncthreads();
    for (int off = 1; off < 128; off <<= 1) {
        int u = (t < 128 && t >= off) ? sc[t - off] : 0;
        __syncthreads();
        if (t < 128) sc[t] += u;
        __syncthreads();
    }
    if (t < 128) { lbase[t] = sc[t] - hist[t]; loff[t] = 0; }
    __syncthreads();
    if (t < 128 && dbase + t < N_NODES) rowptr[dbase + t] = gb + lbase[t];
    for (int j = t; j < nF; j += 256) {
        int2 e = eb[j];
        int r = e.y - dbase;
        int p = lbase[r] + atomicAdd(&loff[r], 1);
        cs[p] = e.x;
    }
    __syncthreads();
    for (int j = t; j < nF; j += 256) col[gb + j] = cs[j];
}

// ---------------------------------------------------------------------------
// Fused GAT aggregate: one wave per dst node; 4 edge slots x 16 lanes;
// bf16 h gather (uint2 = 4 channels), fp32 accumulate.
// ---------------------------------------------------------------------------
template <bool RELU>
__global__ __launch_bounds__(256) void k_gat_agg(const int* __restrict__ rowptr,
        const int* __restrict__ col, const unsigned short* __restrict__ hb,
        const float* __restrict__ as_, const float* __restrict__ ad_,
        const float* __restrict__ bias, float* __restrict__ outagg) {
    int lane = threadIdx.x & 63;
    int d = blockIdx.x * 4 + (threadIdx.x >> 6);
    if (d >= N_NODES) return;
    int slot = lane >> 4;
    int ch   = (lane & 15) * 4;
    int beg = rowptr[d], end = rowptr[d + 1];
    float add = ad_[d];
    float ax = 0.f, ay = 0.f, az = 0.f, aw = 0.f, den = 0.f;
    for (int c = beg; c < end; c += 64) {
        int n = end - c;
        int sj = 0; float wj = 0.f;
        if (lane < n) {
            sj = col[c + lane];
            float e = as_[sj] + add;
            e = (e > 0.f) ? e : NEG_SLOPE * e;
            wj = __expf(e);
        }
        int m = (n < 64) ? n : 64;
        int iters = (m + 3) >> 2;
        for (int j = 0; j < iters; ++j) {
            int sl = j * 4 + slot;
            int   s = __shfl(sj, sl, 64);
            float w = __shfl(wj, sl, 64);   // 0 for out-of-range slots
            den += w;
            uint2 hv = *(const uint2*)(hb + (size_t)s * HID + ch);
            float h0 = __uint_as_float(hv.x << 16);
            float h1 = __uint_as_float(hv.x & 0xffff0000u);
            float h2 = __uint_as_float(hv.y << 16);
            float h3 = __uint_as_float(hv.y & 0xffff0000u);
            ax = fmaf(w, h0, ax);
            ay = fmaf(w, h1, ay);
            az = fmaf(w, h2, az);
            aw = fmaf(w, h3, aw);
        }
    }
    #pragma unroll
    for (int off = 16; off <= 32; off <<= 1) {
        ax  += __shfl_xor(ax,  off, 64);
        ay  += __shfl_xor(ay,  off, 64);
        az  += __shfl_xor(az,  off, 64);
        aw  += __shfl_xor(aw,  off, 64);
        den += __shfl_xor(den, off, 64);
    }
    if (slot == 0) {
        float inv = 1.f / (den + 1e-16f);
        const float4 bv = *(const float4*)(bias + ch);
        float4 o;
        o.x = ax * inv + bv.x;
        o.y = ay * inv + bv.y;
        o.z = az * inv + bv.z;
        o.w = aw * inv + bv.w;
        if (RELU) {
            o.x = fmaxf(o.x, 0.f); o.y = fmaxf(o.y, 0.f);
            o.z = fmaxf(o.z, 0.f); o.w = fmaxf(o.w, 0.f);
        }
        *(float4*)(outagg + (size_t)d * HID + ch) = o;
    }
}

// ---------------------------------------------------------------------------
// logits = agg @ W2 + b2 ; out = log_softmax. 4-wave column split (10 cols
// each); logits tile in LDS (xs reused, pitch 44); lane-local lse; coalesced
// fused store.
// ---------------------------------------------------------------------------
__global__ __launch_bounds__(256) void k_final(const float* __restrict__ agg,
        const float* __restrict__ W2, const float* __restrict__ b2,
        float* __restrict__ out) {
    __shared__ float xs[64 * 68];
    __shared__ float lsev[64];
    int t = threadIdx.x;
    int lane = t & 63;
    int w = t >> 6;
    int cbase = w * 10;
    int base = blockIdx.x * 64;
    int rem = N_NODES - base; if (rem > 64) rem = 64;

    #pragma unroll
    for (int j = 0; j < 4; ++j) {
        int idx = j * 256 + t;
        int r = idx >> 4, c4 = idx & 15;
        int gr = base + r; if (gr >= N_NODES) gr = N_NODES - 1;
        float4 v = *(const float4*)(agg + (size_t)gr * HID + c4 * 4);
        *(float4*)(xs + r * 68 + c4 * 4) = v;
    }
    __syncthreads();

    float acc[10];
    #pragma unroll
    for (int c = 0; c < 10; ++c) acc[c] = b2[cbase + c];
    const float* xrow = xs + lane * 68;
    #pragma unroll 4
    for (int k4 = 0; k4 < 16; ++k4) {
        float4 xv = *(const float4*)(xrow + 4 * k4);
        int kb = 4 * k4 * N_CLASS + cbase;
        #pragma unroll
        for (int c = 0; c < 10; ++c) {
            acc[c] = fmaf(xv.x, W2[kb + c],               acc[c]);
            acc[c] = fmaf(xv.y, W2[kb + N_CLASS + c],     acc[c]);
            acc[c] = fmaf(xv.z, W2[kb + 2 * N_CLASS + c], acc[c]);
            acc[c] = fmaf(xv.w, W2[kb + 3 * N_CLASS + c], acc[c]);
        }
    }
    __syncthreads();                       // all K-loops done; xs reusable
    #pragma unroll
    for (int c = 0; c < 10; ++c) xs[lane * 44 + cbase + c] = acc[c];
    __syncthreads();
    if (t < 64) {
        const float* lr = xs + t * 44;
        float m = lr[0];
        #pragma unroll
        for (int c = 1; c < N_CLASS; ++c) m = fmaxf(m, lr[c]);
        float ss = 0.f;
        #pragma unroll
        for (int c = 0; c < N_CLASS; ++c) ss += __expf(lr[c] - m);
        lsev[t] = m + logf(ss);
    }
    __syncthreads();
    #pragma unroll
    for (int j = 0; j < 3; ++j) {
        int idx = j * 256 + t;             // float4 index, 10 per row
        if (idx < rem * 10) {
            int r = idx / 10, c4 = idx - r * 10;
            float l = lsev[r];
            const float* p = xs + r * 44 + c4 * 4;
            float4 v;
            v.x = p[0] - l; v.y = p[1] - l; v.z = p[2] - l; v.w = p[3] - l;
            *(float4*)(out + (size_t)base * N_CLASS + idx * 4) = v;
        }
    }
}

// ---------------------------------------------------------------------------
extern "C" void kernel_launch(void* const* d_in, const int* in_sizes, int n_in,
                              void* d_out, int out_size, void* d_ws, size_t ws_size,
                              hipStream_t stream) {
    const float* x     = (const float*)d_in[0];
    const int*   ei    = (const int*)  d_in[1];
    const float* W1    = (const float*)d_in[2];
    const float* b1    = (const float*)d_in[3];
    const float* Wc0   = (const float*)d_in[4];
    const float* as0   = (const float*)d_in[5];
    const float* ad0   = (const float*)d_in[6];
    const float* bias0 = (const float*)d_in[7];
    const float* Wc1   = (const float*)d_in[8];
    const float* as1   = (const float*)d_in[9];
    const float* ad1   = (const float*)d_in[10];
    const float* bias1 = (const float*)d_in[11];
    const float* W2    = (const float*)d_in[12];
    const float* b2    = (const float*)d_in[13];
    float* out = (float*)d_out;

    // Workspace layout (~59 MB). Staging overlays:
    //   buf1 (16.5 MB int2) on buf_g region — dead before first gemm_att
    //   buf2 (16.4 MB int2) on buf_h region — dead before lin1
    //   hb (bf16 h, 12.8 MB) lives in buf_g region
    float* buf_h  = (float*)d_ws;                      // N*64 f
    float* buf_g  = buf_h + (size_t)N_NODES * HID;     // N*64 f (region)
    float* as_    = buf_g + (size_t)N_NODES * HID;     // N f
    float* ad_    = as_ + N_NODES;                     // N f
    int*   rowptr = (int*)(ad_ + N_NODES);             // N+1 i
    int*   col    = rowptr + (N_NODES + 1);            // ET i
    int*   tail1  = col + ET;                          // 7 i
    int*   fcnt   = tail1 + NCB;                       // 782 i
    int*   fbase  = fcnt + NFB;                        // 782 i
    int2*  buf1   = (int2*)buf_g;
    int2*  buf2   = (int2*)buf_h;
    unsigned short* hb = (unsigned short*)buf_g;       // bf16 h

    const int AGG_BLOCKS = (N_NODES + 3) / 4;

    // ---- CSR build via 2-level LDS-staged partition (once; reused twice) ----
    hipMemsetAsync(tail1, 0, (NCB + NFB) * sizeof(int), stream);
    k_part1<<<NT1, 256, 0, stream>>>(ei, tail1, buf1);
    k_part2<<<NCB * BPC, 256, 0, stream>>>(buf1, tail1, fcnt, buf2);
    k_fscan<<<1, 1024, 0, stream>>>(fcnt, fbase, rowptr);
    k_part3<<<NFB, 256, 0, stream>>>(buf2, fcnt, fbase, rowptr, col);

    // h0 = relu(x@W1+b1) -> buf_h
    k_lin1<<<ROW_BLOCKS, 256, 0, stream>>>(x, W1, b1, buf_h);

    // ---- GAT layer 0 ----  (bias0 + relu fused into aggregate epilogue)
    k_gemm_att<<<ROW_BLOCKS, 256, 0, stream>>>(buf_h, Wc0, as0, ad0,
                                               hb, as_, ad_);
    k_gat_agg<true><<<AGG_BLOCKS, 256, 0, stream>>>(rowptr, col, hb,
                                                    as_, ad_, bias0, buf_h);

    // ---- GAT layer 1 ----  (bias1 fused, no relu)
    k_gemm_att<<<ROW_BLOCKS, 256, 0, stream>>>(buf_h, Wc1, as1, ad1,
                                               hb, as_, ad_);
    k_gat_agg<false><<<AGG_BLOCKS, 256, 0, stream>>>(rowptr, col, hb,
                                                     as_, ad_, bias1, buf_h);

    // logits + log_softmax
    k_final<<<ROW_BLOCKS, 256, 0, stream>>>(buf_h, W2, b2, out);
}

// Round 8
// 347.197 us; speedup vs baseline: 1.5232x; 1.5232x over previous
//
#include <hip/hip_runtime.h>

#define N_NODES 100000
#define N_EDGES 1600000
#define F_IN    128
#define HID     64
#define N_CLASS 40
#define NEG_SLOPE 0.2f
#define ET (N_EDGES + N_NODES)          // 1,700,000
#define ROW_BLOCKS ((N_NODES + 63) / 64)

// ---- 2-level radix partition geometry ----
#define NCB   7
#define CAP1  294912
#define BPC   144
#define NFB   782
#define CAPF  2624
#define NT1   ((ET + 2047) / 2048)

typedef __attribute__((ext_vector_type(8))) short bf16x8;
typedef __attribute__((ext_vector_type(4))) float f32x4;

__device__ __forceinline__ unsigned int f2bf(float f) {  // fp32 -> bf16 (RNE)
    unsigned int u = __float_as_uint(f);
    return (u + 0x7fffu + ((u >> 16) & 1u)) >> 16;
}

// ---------------------------------------------------------------------------
// Weight prep: bf16 transposed [n][k] so MFMA B-frags are contiguous 16 B.
// ---------------------------------------------------------------------------
__global__ __launch_bounds__(256) void k_prepw(const float* __restrict__ W1,
        const float* __restrict__ Wc0, const float* __restrict__ Wc1,
        unsigned short* __restrict__ Wt1, unsigned short* __restrict__ Wtc0,
        unsigned short* __restrict__ Wtc1) {
    int t = threadIdx.x;
    for (int i = t; i < F_IN * HID; i += 256) {
        int k = i >> 6, n = i & 63;
        Wt1[n * F_IN + k] = (unsigned short)f2bf(W1[i]);
    }
    for (int i = t; i < HID * HID; i += 256) {
        int k = i >> 6, n = i & 63;
        Wtc0[n * HID + k] = (unsigned short)f2bf(Wc0[i]);
        Wtc1[n * HID + k] = (unsigned short)f2bf(Wc1[i]);
    }
}

// ---------------------------------------------------------------------------
// h0 = relu(x @ W1 + b1) via MFMA 16x16x32 bf16. Block = 4 waves = 64 rows.
// Wave: 16 rows x 64 cols, K=128 (4 chunks), B-frags in VGPRs. Output bf16.
// ---------------------------------------------------------------------------
__global__ __launch_bounds__(256) void k_lin1(const float* __restrict__ x,
        const unsigned short* __restrict__ Wt1, const float* __restrict__ b1,
        unsigned short* __restrict__ h0b) {
    __shared__ float xs[4][16 * 68];
    int t = threadIdx.x;
    int lane = t & 63, w = t >> 6;
    int quad = lane >> 4, lr = lane & 15;
    int rowg0 = blockIdx.x * 64 + w * 16;

    bf16x8 bfr[4][4];                       // [kc][nt]
    #pragma unroll
    for (int kc = 0; kc < 4; ++kc)
        #pragma unroll
        for (int nt = 0; nt < 4; ++nt)
            bfr[kc][nt] = *(const bf16x8*)(Wt1 + (nt * 16 + lr) * F_IN
                                           + kc * 32 + quad * 8);
    f32x4 zero = {0.f, 0.f, 0.f, 0.f};
    f32x4 acc[4] = {zero, zero, zero, zero};

    int arow = rowg0 + lr; if (arow >= N_NODES) arow = N_NODES - 1;
    const float* ab = x + (size_t)arow * F_IN;
    #pragma unroll
    for (int kc = 0; kc < 4; ++kc) {
        const float* ap = ab + kc * 32 + quad * 8;
        float4 a0 = *(const float4*)ap;
        float4 a1 = *(const float4*)(ap + 4);
        union { bf16x8 v; unsigned int u[4]; } af;
        af.u[0] = f2bf(a0.x) | (f2bf(a0.y) << 16);
        af.u[1] = f2bf(a0.z) | (f2bf(a0.w) << 16);
        af.u[2] = f2bf(a1.x) | (f2bf(a1.y) << 16);
        af.u[3] = f2bf(a1.z) | (f2bf(a1.w) << 16);
        #pragma unroll
        for (int nt = 0; nt < 4; ++nt)
            acc[nt] = __builtin_amdgcn_mfma_f32_16x16x32_bf16(
                          af.v, bfr[kc][nt], acc[nt], 0, 0, 0);
    }
    // bias + relu -> LDS (C layout: row=quad*4+reg, col=nt*16+lr)
    #pragma unroll
    for (int nt = 0; nt < 4; ++nt) {
        float bv = b1[nt * 16 + lr];
        #pragma unroll
        for (int reg = 0; reg < 4; ++reg)
            xs[w][(quad * 4 + reg) * 68 + nt * 16 + lr] =
                fmaxf(acc[nt][reg] + bv, 0.f);
    }
    __syncthreads();
    #pragma unroll
    for (int j = 0; j < 2; ++j) {
        int task = j * 64 + lane;           // 16 rows x 8 col-groups
        int r = task >> 3, g = task & 7;
        int grow = blockIdx.x * 64 + w * 16 + r;
        if (grow < N_NODES) {
            const float* p = xs[w] + r * 68 + g * 8;
            uint4 u;
            u.x = f2bf(p[0]) | (f2bf(p[1]) << 16);
            u.y = f2bf(p[2]) | (f2bf(p[3]) << 16);
            u.z = f2bf(p[4]) | (f2bf(p[5]) << 16);
            u.w = f2bf(p[6]) | (f2bf(p[7]) << 16);
            *(uint4*)(h0b + (size_t)grow * HID + g * 8) = u;
        }
    }
}

// ---------------------------------------------------------------------------
// h = hin @ Wc (MFMA, bf16 in/out) ; as_ = h@att_src ; ad_ = h@att_dst.
// ---------------------------------------------------------------------------
__global__ __launch_bounds__(256) void k_gemm_att(
        const unsigned short* __restrict__ hin,
        const unsigned short* __restrict__ Wt,
        const float* __restrict__ att_s, const float* __restrict__ att_d,
        unsigned short* __restrict__ hb, float* __restrict__ as_,
        float* __restrict__ ad_) {
    __shared__ float xs[4][16 * 68];
    int t = threadIdx.x;
    int lane = t & 63, w = t >> 6;
    int quad = lane >> 4, lr = lane & 15;
    int rowg0 = blockIdx.x * 64 + w * 16;

    bf16x8 bfr[2][4];
    #pragma unroll
    for (int kc = 0; kc < 2; ++kc)
        #pragma unroll
        for (int nt = 0; nt < 4; ++nt)
            bfr[kc][nt] = *(const bf16x8*)(Wt + (nt * 16 + lr) * HID
                                           + kc * 32 + quad * 8);
    f32x4 zero = {0.f, 0.f, 0.f, 0.f};
    f32x4 acc[4] = {zero, zero, zero, zero};

    int arow = rowg0 + lr; if (arow >= N_NODES) arow = N_NODES - 1;
    #pragma unroll
    for (int kc = 0; kc < 2; ++kc) {
        bf16x8 af = *(const bf16x8*)(hin + (size_t)arow * HID
                                     + kc * 32 + quad * 8);
        #pragma unroll
        for (int nt = 0; nt < 4; ++nt)
            acc[nt] = __builtin_amdgcn_mfma_f32_16x16x32_bf16(
                          af, bfr[kc][nt], acc[nt], 0, 0, 0);
    }
    // attention dots: per-lane partial over its column, reduce within quad
    float asv[4], adv[4];
    #pragma unroll
    for (int nt = 0; nt < 4; ++nt) {
        asv[nt] = att_s[nt * 16 + lr];
        adv[nt] = att_d[nt * 16 + lr];
    }
    #pragma unroll
    for (int reg = 0; reg < 4; ++reg) {
        float p1 = acc[0][reg] * asv[0] + acc[1][reg] * asv[1]
                 + acc[2][reg] * asv[2] + acc[3][reg] * asv[3];
        float p2 = acc[0][reg] * adv[0] + acc[1][reg] * adv[1]
                 + acc[2][reg] * adv[2] + acc[3][reg] * adv[3];
        #pragma unroll
        for (int off = 1; off < 16; off <<= 1) {
            p1 += __shfl_xor(p1, off, 64);
            p2 += __shfl_xor(p2, off, 64);
        }
        if (lr == 0) {
            int grow = rowg0 + quad * 4 + reg;
            if (grow < N_NODES) { as_[grow] = p1; ad_[grow] = p2; }
        }
    }
    // h -> LDS -> bf16 coalesced store
    #pragma unroll
    for (int nt = 0; nt < 4; ++nt)
        #pragma unroll
        for (int reg = 0; reg < 4; ++reg)
            xs[w][(quad * 4 + reg) * 68 + nt * 16 + lr] = acc[nt][reg];
    __syncthreads();
    #pragma unroll
    for (int j = 0; j < 2; ++j) {
        int task = j * 64 + lane;
        int r = task >> 3, g = task & 7;
        int grow = blockIdx.x * 64 + w * 16 + r;
        if (grow < N_NODES) {
            const float* p = xs[w] + r * 68 + g * 8;
            uint4 u;
            u.x = f2bf(p[0]) | (f2bf(p[1]) << 16);
            u.y = f2bf(p[2]) | (f2bf(p[3]) << 16);
            u.z = f2bf(p[4]) | (f2bf(p[5]) << 16);
            u.w = f2bf(p[6]) | (f2bf(p[7]) << 16);
            *(uint4*)(hb + (size_t)grow * HID + g * 8) = u;
        }
    }
}

// ---------------------------------------------------------------------------
// Partition level 1: edges -> 7 coarse buckets (dst>>14).
// ---------------------------------------------------------------------------
__global__ __launch_bounds__(256) void k_part1(const int* __restrict__ ei,
        int* __restrict__ tail1, int2* __restrict__ buf1) {
    __shared__ int2 eb[2048];
    __shared__ int hist[NCB], lbase[NCB], loff[NCB], goff[NCB];
    int t = threadIdx.x;
    int tileBase = blockIdx.x * 2048;
    int total = ET - tileBase; if (total > 2048) total = 2048;
    if (t < NCB) hist[t] = 0;
    __syncthreads();

    int sr[8], dr[8];
    #pragma unroll
    for (int r = 0; r < 8; ++r) {
        int i = tileBase + r * 256 + t;
        int s = -1, d = -1;
        if (i < ET) {
            if (i < N_EDGES) { s = ei[i]; d = ei[N_EDGES + i]; }
            else             { s = d = i - N_EDGES; }
            atomicAdd(&hist[d >> 14], 1);
        }
        sr[r] = s; dr[r] = d;
    }
    __syncthreads();
    if (t == 0) {
        int run = 0;
        for (int b = 0; b < NCB; ++b) { lbase[b] = run; loff[b] = 0; run += hist[b]; }
    }
    __syncthreads();
    if (t < NCB && hist[t] > 0) goff[t] = atomicAdd(&tail1[t], hist[t]);
    #pragma unroll
    for (int r = 0; r < 8; ++r) {
        if (dr[r] >= 0) {
            int b = dr[r] >> 14;
            int p = lbase[b] + atomicAdd(&loff[b], 1);
            eb[p] = make_int2(sr[r], dr[r]);
        }
    }
    __syncthreads();
    for (int j = t; j < total; j += 256) {
        int2 e = eb[j];
        int b = e.y >> 14;
        buf1[(size_t)b * CAP1 + goff[b] + (j - lbase[b])] = e;
    }
}

// ---------------------------------------------------------------------------
// Partition level 2: coarse bucket -> 128 fine buckets (128-dst ranges).
// ---------------------------------------------------------------------------
__global__ __launch_bounds__(256) void k_part2(const int2* __restrict__ buf1,
        const int* __restrict__ tail1, int* __restrict__ fcnt,
        int2* __restrict__ buf2) {
    __shared__ int2 eb[2048];
    __shared__ int hist[128], lbase[128], loff[128], goff[128], sc[128];
    int t = threadIdx.x;
    int cb   = blockIdx.x / BPC;
    int tile = blockIdx.x % BPC;
    int n1 = tail1[cb];
    int base = tile * 2048;
    if (base >= n1) return;
    int total = n1 - base; if (total > 2048) total = 2048;
    if (t < 128) hist[t] = 0;
    __syncthreads();

    int sr[8], dr[8];
    #pragma unroll
    for (int r = 0; r < 8; ++r) {
        int i = base + r * 256 + t;
        int s = -1, d = -1;
        if (i < n1) {
            int2 e = buf1[(size_t)cb * CAP1 + i];
            s = e.x; d = e.y;
            atomicAdd(&hist[(d >> 7) & 127], 1);
        }
        sr[r] = s; dr[r] = d;
    }
    __syncthreads();
    if (t < 128) sc[t] = hist[t];
    __syncthreads();
    for (int off = 1; off < 128; off <<= 1) {
        int u = (t < 128 && t >= off) ? sc[t - off] : 0;
        __syncthreads();
        if (t < 128) sc[t] += u;
        __syncthreads();
    }
    if (t < 128) { lbase[t] = sc[t] - hist[t]; loff[t] = 0; }
    __syncthreads();
    if (t < 128 && hist[t] > 0)
        goff[t] = atomicAdd(&fcnt[cb * 128 + t], hist[t]);
    #pragma unroll
    for (int r = 0; r < 8; ++r) {
        if (dr[r] >= 0) {
            int f = (dr[r] >> 7) & 127;
            int p = lbase[f] + atomicAdd(&loff[f], 1);
            eb[p] = make_int2(sr[r], dr[r]);
        }
    }
    __syncthreads();
    for (int j = t; j < total; j += 256) {
        int2 e = eb[j];
        int f = (e.y >> 7) & 127;
        buf2[(size_t)(e.y >> 7) * CAPF + goff[f] + (j - lbase[f])] = e;
    }
}

// ---------------------------------------------------------------------------
__global__ __launch_bounds__(1024) void k_fscan(const int* __restrict__ fcnt,
        int* __restrict__ fbase, int* __restrict__ rowptr) {
    __shared__ int s[1024];
    int t = threadIdx.x;
    int v = (t < NFB) ? fcnt[t] : 0;
    s[t] = v;
    __syncthreads();
    for (int off = 1; off < 1024; off <<= 1) {
        int u = (t >= off) ? s[t - off] : 0;
        __syncthreads();
        s[t] += u;
        __syncthreads();
    }
    if (t < NFB) fbase[t] = s[t] - v;
    if (t == 0) rowptr[N_NODES] = ET;
}

// ---------------------------------------------------------------------------
// Partition level 3: fine bucket -> exact per-node CSR.
// ---------------------------------------------------------------------------
__global__ __launch_bounds__(256) void k_part3(const int2* __restrict__ buf2,
        const int* __restrict__ fcnt, const int* __restrict__ fbase,
        int* __restrict__ rowptr, int* __restrict__ col) {
    __shared__ int2 eb[CAPF];
    __shared__ int cs[CAPF];
    __shared__ int hist[128], lbase[128], loff[128], sc[128];
    int t = threadIdx.x;
    int fb = blockIdx.x;
    int nF = fcnt[fb];
    int gb = fbase[fb];
    int dbase = fb * 128;
    if (t < 128) hist[t] = 0;
    __syncthreads();
    for (int j = t; j < nF; j += 256) {
        int2 e = buf2[(size_t)fb * CAPF + j];
        eb[j] = e;
        atomicAdd(&hist[e.y - dbase], 1);
    }
    __syncthreads();
    if (t < 128) sc[t] = hist[t];
    __syncthreads();
    for (int off = 1; off < 128; off <<= 1) {
        int u = (t < 128 && t >= off) ? sc[t - off] : 0;
        __syncthreads();
        if (t < 128) sc[t] += u;
        __syncthreads();
    }
    if (t < 128) { lbase[t] = sc[t] - hist[t]; loff[t] = 0; }
    __syncthreads();
    if (t < 128 && dbase + t < N_NODES) rowptr[dbase + t] = gb + lbase[t];
    for (int j = t; j < nF; j += 256) {
        int2 e = eb[j];
        int r = e.y - dbase;
        int p = lbase[r] + atomicAdd(&loff[r], 1);
        cs[p] = e.x;
    }
    __syncthreads();
    for (int j = t; j < nF; j += 256) col[gb + j] = cs[j];
}

// ---------------------------------------------------------------------------
// Fused GAT aggregate: one wave per dst node; bf16 h gather, fp32 accumulate.
// Layer 0 emits bf16 (+bias0+relu) for the next MFMA; layer 1 emits fp32.
// ---------------------------------------------------------------------------
template <bool RELU, bool BF16OUT>
__global__ __launch_bounds__(256) void k_gat_agg(const int* __restrict__ rowptr,
        const int* __restrict__ col, const unsigned short* __restrict__ hb,
        const float* __restrict__ as_, const float* __restrict__ ad_,
        const float* __restrict__ bias, unsigned short* __restrict__ outb,
        float* __restrict__ outf) {
    int lane = threadIdx.x & 63;
    int d = blockIdx.x * 4 + (threadIdx.x >> 6);
    if (d >= N_NODES) return;
    int slot = lane >> 4;
    int ch   = (lane & 15) * 4;
    int beg = rowptr[d], end = rowptr[d + 1];
    float add = ad_[d];
    float ax = 0.f, ay = 0.f, az = 0.f, aw = 0.f, den = 0.f;
    for (int c = beg; c < end; c += 64) {
        int n = end - c;
        int sj = 0; float wj = 0.f;
        if (lane < n) {
            sj = col[c + lane];
            float e = as_[sj] + add;
            e = (e > 0.f) ? e : NEG_SLOPE * e;
            wj = __expf(e);
        }
        int m = (n < 64) ? n : 64;
        int iters = (m + 3) >> 2;
        for (int j = 0; j < iters; ++j) {
            int sl = j * 4 + slot;
            int   s = __shfl(sj, sl, 64);
            float w = __shfl(wj, sl, 64);
            den += w;
            uint2 hv = *(const uint2*)(hb + (size_t)s * HID + ch);
            float h0 = __uint_as_float(hv.x << 16);
            float h1 = __uint_as_float(hv.x & 0xffff0000u);
            float h2 = __uint_as_float(hv.y << 16);
            float h3 = __uint_as_float(hv.y & 0xffff0000u);
            ax = fmaf(w, h0, ax);
            ay = fmaf(w, h1, ay);
            az = fmaf(w, h2, az);
            aw = fmaf(w, h3, aw);
        }
    }
    #pragma unroll
    for (int off = 16; off <= 32; off <<= 1) {
        ax  += __shfl_xor(ax,  off, 64);
        ay  += __shfl_xor(ay,  off, 64);
        az  += __shfl_xor(az,  off, 64);
        aw  += __shfl_xor(aw,  off, 64);
        den += __shfl_xor(den, off, 64);
    }
    if (slot == 0) {
        float inv = 1.f / (den + 1e-16f);
        const float4 bv = *(const float4*)(bias + ch);
        float4 o;
        o.x = ax * inv + bv.x;
        o.y = ay * inv + bv.y;
        o.z = az * inv + bv.z;
        o.w = aw * inv + bv.w;
        if (RELU) {
            o.x = fmaxf(o.x, 0.f); o.y = fmaxf(o.y, 0.f);
            o.z = fmaxf(o.z, 0.f); o.w = fmaxf(o.w, 0.f);
        }
        if (BF16OUT) {
            uint2 u;
            u.x = f2bf(o.x) | (f2bf(o.y) << 16);
            u.y = f2bf(o.z) | (f2bf(o.w) << 16);
            *(uint2*)(outb + (size_t)d * HID + ch) = u;
        } else {
            *(float4*)(outf + (size_t)d * HID + ch) = o;
        }
    }
}

// ---------------------------------------------------------------------------
// logits = agg @ W2 + b2 ; out = log_softmax. (r6 64-thread version.)
// ---------------------------------------------------------------------------
__global__ __launch_bounds__(64) void k_final(const float* __restrict__ agg,
        const float* __restrict__ W2, const float* __restrict__ b2,
        float* __restrict__ out) {
    __shared__ float xs[64 * 68];
    int lane = threadIdx.x;
    int base = blockIdx.x * 64;
    int rem = N_NODES - base; if (rem > 64) rem = 64;

    #pragma unroll
    for (int j = 0; j < 16; ++j) {
        int idx = j * 64 + lane;
        int r   = idx >> 4;
        int c4  = idx & 15;
        int gr  = base + r; if (gr >= N_NODES) gr = N_NODES - 1;
        float4 v = *(const float4*)(agg + (size_t)gr * HID + c4 * 4);
        *(float4*)(xs + r * 68 + c4 * 4) = v;
    }
    __syncthreads();

    float acc[N_CLASS];
    #pragma unroll
    for (int c = 0; c < N_CLASS; ++c) acc[c] = b2[c];
    const float* xrow = xs + lane * 68;
    #pragma unroll 2
    for (int k4 = 0; k4 < 16; ++k4) {
        float4 xv = *(const float4*)(xrow + 4 * k4);
        int kb = 4 * k4 * N_CLASS;
        #pragma unroll
        for (int c = 0; c < N_CLASS; ++c) {
            acc[c] = fmaf(xv.x, W2[kb + c],               acc[c]);
            acc[c] = fmaf(xv.y, W2[kb + N_CLASS + c],     acc[c]);
            acc[c] = fmaf(xv.z, W2[kb + 2 * N_CLASS + c], acc[c]);
            acc[c] = fmaf(xv.w, W2[kb + 3 * N_CLASS + c], acc[c]);
        }
    }
    float m = acc[0];
    #pragma unroll
    for (int c = 1; c < N_CLASS; ++c) m = fmaxf(m, acc[c]);
    float ssum = 0.f;
    #pragma unroll
    for (int c = 0; c < N_CLASS; ++c) ssum += __expf(acc[c] - m);
    float lse = m + logf(ssum);

    __syncthreads();
    #pragma unroll
    for (int c4 = 0; c4 < 10; ++c4) {
        float4 o;
        o.x = acc[4 * c4 + 0] - lse; o.y = acc[4 * c4 + 1] - lse;
        o.z = acc[4 * c4 + 2] - lse; o.w = acc[4 * c4 + 3] - lse;
        *(float4*)(xs + lane * N_CLASS + c4 * 4) = o;
    }
    __syncthreads();
    #pragma unroll
    for (int j = 0; j < 10; ++j) {
        int idx = j * 64 + lane;
        if (idx < rem * 10) {
            float4 v = *(const float4*)(xs + idx * 4);
            *(float4*)(out + (size_t)base * N_CLASS + idx * 4) = v;
        }
    }
}

// ---------------------------------------------------------------------------
extern "C" void kernel_launch(void* const* d_in, const int* in_sizes, int n_in,
                              void* d_out, int out_size, void* d_ws, size_t ws_size,
                              hipStream_t stream) {
    const float* x     = (const float*)d_in[0];
    const int*   ei    = (const int*)  d_in[1];
    const float* W1    = (const float*)d_in[2];
    const float* b1    = (const float*)d_in[3];
    const float* Wc0   = (const float*)d_in[4];
    const float* as0   = (const float*)d_in[5];
    const float* ad0   = (const float*)d_in[6];
    const float* bias0 = (const float*)d_in[7];
    const float* Wc1   = (const float*)d_in[8];
    const float* as1   = (const float*)d_in[9];
    const float* ad1   = (const float*)d_in[10];
    const float* bias1 = (const float*)d_in[11];
    const float* W2    = (const float*)d_in[12];
    const float* b2    = (const float*)d_in[13];
    float* out = (float*)d_out;

    // Workspace (~59.3 MB), overlaid regions:
    // R1 (25.6 MB): buf2 (part2->part3) -> h0b bf16 (lin1->gemm_att0)
    //               -> agg1 f32 (agg L1 -> final)
    // R2 (25.6 MB): buf1 (part1->part2) -> hb bf16 @0 + agg0b bf16 @12.8MB
    char* base = (char*)d_ws;
    char* R1 = base;
    char* R2 = base + (size_t)N_NODES * HID * 4;
    unsigned short* h0b  = (unsigned short*)R1;
    float*          agg1 = (float*)R1;
    int2*           buf2 = (int2*)R1;
    unsigned short* hb   = (unsigned short*)R2;
    unsigned short* agg0b = (unsigned short*)(R2 + (size_t)N_NODES * HID * 2);
    int2*           buf1 = (int2*)R2;

    char* mp = R2 + (size_t)N_NODES * HID * 4;
    unsigned short* Wt1  = (unsigned short*)mp;  mp += F_IN * HID * 2;
    unsigned short* Wtc0 = (unsigned short*)mp;  mp += HID * HID * 2;
    unsigned short* Wtc1 = (unsigned short*)mp;  mp += HID * HID * 2;
    float* as_   = (float*)mp;                   mp += N_NODES * 4;
    float* ad_   = (float*)mp;                   mp += N_NODES * 4;
    int*   col   = (int*)mp;                     mp += (size_t)ET * 4;
    int*   tail1 = (int*)mp;                     mp += NCB * 4;
    int*   fcnt  = (int*)mp;                     mp += NFB * 4;
    int*   fbase = (int*)mp;                     mp += NFB * 4;
    int*   rowptr= (int*)mp;

    const int AGG_BLOCKS = (N_NODES + 3) / 4;

    // ---- CSR build (once) + weight prep ----
    hipMemsetAsync(tail1, 0, (NCB + NFB) * sizeof(int), stream);
    k_prepw<<<1, 256, 0, stream>>>(W1, Wc0, Wc1, Wt1, Wtc0, Wtc1);
    k_part1<<<NT1, 256, 0, stream>>>(ei, tail1, buf1);
    k_part2<<<NCB * BPC, 256, 0, stream>>>(buf1, tail1, fcnt, buf2);
    k_fscan<<<1, 1024, 0, stream>>>(fcnt, fbase, rowptr);
    k_part3<<<NFB, 256, 0, stream>>>(buf2, fcnt, fbase, rowptr, col);

    // h0 = relu(x@W1+b1) -> h0b (bf16)
    k_lin1<<<ROW_BLOCKS, 256, 0, stream>>>(x, Wt1, b1, h0b);

    // ---- GAT layer 0 ----
    k_gemm_att<<<ROW_BLOCKS, 256, 0, stream>>>(h0b, Wtc0, as0, ad0,
                                               hb, as_, ad_);
    k_gat_agg<true, true><<<AGG_BLOCKS, 256, 0, stream>>>(
        rowptr, col, hb, as_, ad_, bias0, agg0b, (float*)nullptr);

    // ---- GAT layer 1 ----
    k_gemm_att<<<ROW_BLOCKS, 256, 0, stream>>>(agg0b, Wtc1, as1, ad1,
                                               hb, as_, ad_);
    k_gat_agg<false, false><<<AGG_BLOCKS, 256, 0, stream>>>(
        rowptr, col, hb, as_, ad_, bias1, (unsigned short*)nullptr, agg1);

    // logits + log_softmax
    k_final<<<ROW_BLOCKS, 64, 0, stream>>>(agg1, W2, b2, out);
}